// Round 4
// baseline (621.772 us; speedup 1.0000x reference)
//
#include <hip/hip_runtime.h>
#include <stdint.h>

// ---------------- types / helpers ----------------
using bf16x8 = __attribute__((ext_vector_type(8))) short;   // 8 x bf16 (4 VGPRs)
using f32x4  = __attribute__((ext_vector_type(4))) float;

__device__ __forceinline__ f32x4 mfma16(bf16x8 a, bf16x8 b, f32x4 c) {
  return __builtin_amdgcn_mfma_f32_16x16x32_bf16(a, b, c, 0, 0, 0);
}

__device__ __forceinline__ unsigned short f2b_rne(float f) {
  union { float f; unsigned u; } v; v.f = f;
  unsigned r = v.u + 0x7fffu + ((v.u >> 16) & 1u);
  return (unsigned short)(r >> 16);
}

// ---------------- fp32 -> bf16 conversion ----------------
__global__ void f2b_kernel(const float* __restrict__ s, unsigned short* __restrict__ d, int n4) {
  int i = blockIdx.x * 256 + threadIdx.x;
  if (i >= n4) return;
  float4 v = reinterpret_cast<const float4*>(s)[i];
  ushort4 o;
  o.x = f2b_rne(v.x); o.y = f2b_rne(v.y); o.z = f2b_rne(v.z); o.w = f2b_rne(v.w);
  reinterpret_cast<ushort4*>(d)[i] = o;
}

// ---------------- attn/cross weight composition (fp32): W_eff = Wo @ Wv, b_eff = Wo @ bv + bo ----
// grid (16, 7): mat 0..5 = layers, 6 = cross. Output W_eff bf16 [256][256] row-major, b_eff f32.
__global__ __launch_bounds__(256) void compose_attn(
    const float* __restrict__ aiW, const float* __restrict__ aib,
    const float* __restrict__ aoW, const float* __restrict__ aob,
    const float* __restrict__ ciW, const float* __restrict__ cib,
    const float* __restrict__ coW, const float* __restrict__ cob,
    unsigned short* __restrict__ wEff, float* __restrict__ bEff) {
  const int mat = blockIdx.y;
  const float* Wo = (mat < 6) ? aoW + (size_t)mat * 65536 : coW;
  const float* Wv = (mat < 6) ? aiW + (size_t)mat * 196608 + 131072 : ciW + 131072;
  const float* bv = (mat < 6) ? aib + mat * 768 + 512 : cib + 512;
  const float* bo = (mat < 6) ? aob + mat * 256 : cob;
  unsigned short* Wd = wEff + (size_t)mat * 65536;
  const int m = blockIdx.x * 16 + (threadIdx.x >> 4);
  const int k0 = (threadIdx.x & 15) * 16;
  float c[16] = {};
  for (int j = 0; j < 256; ++j) {
    const float a = Wo[m * 256 + j];
    const float* Br = Wv + j * 256 + k0;
#pragma unroll
    for (int kk = 0; kk < 16; ++kk) c[kk] = fmaf(a, Br[kk], c[kk]);
  }
#pragma unroll
  for (int kk = 0; kk < 16; ++kk) Wd[m * 256 + k0 + kk] = f2b_rne(c[kk]);
  if (blockIdx.x == 0) {
    const int mm = threadIdx.x;
    float s = 0.f;
    for (int j = 0; j < 256; ++j) s = fmaf(Wo[mm * 256 + j], bv[j], s);
    bEff[mat * 256 + mm] = s + bo[mm];
  }
}

// ---------------- trunk GEMM v2: A-stationary in LDS, W streamed from L2, barrier-free K-loop ----
// Y[4096 x Nout] = A[4096 x K] @ W[Nout x K]^T (+ epilogue)
// ROWS=16: block = 16 rows x 256 cols (4 waves x 64 cols), grid (256,1)   [LN-capable]
// ROWS=32: block = 32 rows x 128 cols (4 waves x 32 cols), grid (128, Nout/128) [elementwise only]
// EPI: 1 = ybf = gelu(C+b) ; 2 = hf/hbf = C+b ; 3 = hf/hbf = LN(hf + C + b) ; 4 = hf/hbf = hf + C + b
template<int EPI, int ROWS, int K>
__global__ __launch_bounds__(256, 4) void gemm_t2(
    const unsigned short* __restrict__ A, const unsigned short* __restrict__ W,
    const float* __restrict__ bias, float* __restrict__ hf,
    unsigned short* __restrict__ ybf, const float* __restrict__ gam,
    const float* __restrict__ bet, int Nout) {
  constexpr int NBF = ROWS / 16;
  constexpr int NCF = (ROWS == 16) ? 4 : 2;
  constexpr int NK = K / 32;
  constexpr int K2 = K * 2;
  __shared__ char smA[ROWS * K2];
  __shared__ float red[2][4][16];
  const int tid = threadIdx.x, wid = tid >> 6, lane = tid & 63;
  const int r = lane & 15, hi = lane >> 4;
  const int row0 = blockIdx.x * ROWS;
  const int colW0 = ((ROWS == 16) ? 0 : blockIdx.y * 128) + wid * (NCF * 16);

  // ---- stage A tile once (reg-staged, XOR-swizzled) ----
  constexpr int CHUNKS = ROWS * K / 8;
  constexpr int CPR = K / 8;
#pragma unroll
  for (int id = tid; id < CHUNKS; id += 256) {
    const int row = id / CPR, c8 = id % CPR;
    bf16x8 v = *reinterpret_cast<const bf16x8*>(A + (size_t)(row0 + row) * K + c8 * 8);
    *reinterpret_cast<bf16x8*>(smA + row * K2 + ((c8 * 16) ^ ((row & 7) << 4))) = v;
  }
  __syncthreads();

  // ---- barrier-free K-loop: a-frags from LDS, W-frags streamed from global (L2) ----
  const unsigned short* Wb = W + (size_t)(colW0 + r) * K + hi * 8;
  f32x4 acc[NBF][NCF] = {};
  bf16x8 wc[NCF], wn[NCF];
#pragma unroll
  for (int cf = 0; cf < NCF; ++cf)
    wc[cf] = *reinterpret_cast<const bf16x8*>(Wb + cf * 16 * K);
#pragma unroll 4
  for (int ks = 0; ks < NK; ++ks) {
    if (ks + 1 < NK) {
#pragma unroll
      for (int cf = 0; cf < NCF; ++cf)
        wn[cf] = *reinterpret_cast<const bf16x8*>(Wb + cf * 16 * K + (ks + 1) * 32);
    }
    bf16x8 av[NBF];
#pragma unroll
    for (int bf = 0; bf < NBF; ++bf)
      av[bf] = *reinterpret_cast<const bf16x8*>(
          smA + (bf * 16 + r) * K2 + ((ks * 64 + hi * 16) ^ ((r & 7) << 4)));
#pragma unroll
    for (int bf = 0; bf < NBF; ++bf)
#pragma unroll
      for (int cf = 0; cf < NCF; ++cf)
        acc[bf][cf] = mfma16(av[bf], wc[cf], acc[bf][cf]);
#pragma unroll
    for (int cf = 0; cf < NCF; ++cf) wc[cf] = wn[cf];
  }

  // ---- epilogue: C[row0 + bf*16 + hi*4 + j][colW0 + cf*16 + r] ----
  if (EPI == 1) {
#pragma unroll
    for (int bf = 0; bf < NBF; ++bf)
#pragma unroll
      for (int cf = 0; cf < NCF; ++cf) {
        const int col = colW0 + cf * 16 + r;
        const float bv = bias[col];
#pragma unroll
        for (int j = 0; j < 4; ++j) {
          const int row = row0 + bf * 16 + hi * 4 + j;
          float y = acc[bf][cf][j] + bv;
          y = 0.5f * y * (1.f + erff(y * 0.70710678118654752f));
          ybf[(size_t)row * Nout + col] = f2b_rne(y);
        }
      }
  } else if (EPI == 2 || EPI == 4) {
#pragma unroll
    for (int bf = 0; bf < NBF; ++bf)
#pragma unroll
      for (int cf = 0; cf < NCF; ++cf) {
        const int col = colW0 + cf * 16 + r;
        const float bv = bias[col];
#pragma unroll
        for (int j = 0; j < 4; ++j) {
          const int row = row0 + bf * 16 + hi * 4 + j;
          float y = acc[bf][cf][j] + bv;
          if (EPI == 4) y += hf[(size_t)row * 256 + col];
          hf[(size_t)row * 256 + col]  = y;
          ybf[(size_t)row * 256 + col] = f2b_rne(y);
        }
      }
  } else {  // EPI == 3 : h = LN(hf + C + bias)   (ROWS==16, NBF==1, 256 cols in-block)
    float xx[4][4];
    float sum[4] = {0.f, 0.f, 0.f, 0.f}, sq[4] = {0.f, 0.f, 0.f, 0.f};
#pragma unroll
    for (int cf = 0; cf < 4; ++cf) {
      const int col = colW0 + cf * 16 + r;
      const float bv = bias[col];
#pragma unroll
      for (int j = 0; j < 4; ++j) {
        float v = hf[(size_t)(row0 + hi * 4 + j) * 256 + col] + acc[0][cf][j] + bv;
        xx[cf][j] = v; sum[j] += v; sq[j] += v * v;
      }
    }
#pragma unroll
    for (int m = 1; m < 16; m <<= 1) {
#pragma unroll
      for (int j = 0; j < 4; ++j) {
        sum[j] += __shfl_xor(sum[j], m, 64);
        sq[j]  += __shfl_xor(sq[j],  m, 64);
      }
    }
    if (r == 0) {
#pragma unroll
      for (int j = 0; j < 4; ++j) { red[0][wid][hi * 4 + j] = sum[j]; red[1][wid][hi * 4 + j] = sq[j]; }
    }
    __syncthreads();
    float mu[4], rs[4];
#pragma unroll
    for (int j = 0; j < 4; ++j) {
      const int rr = hi * 4 + j;
      float ts = red[0][0][rr] + red[0][1][rr] + red[0][2][rr] + red[0][3][rr];
      float tq = red[1][0][rr] + red[1][1][rr] + red[1][2][rr] + red[1][3][rr];
      float mean = ts * (1.f / 256.f);
      mu[j] = mean;
      rs[j] = rsqrtf(tq * (1.f / 256.f) - mean * mean + 1e-5f);
    }
#pragma unroll
    for (int cf = 0; cf < 4; ++cf) {
      const int col = colW0 + cf * 16 + r;
      const float gm = gam[col], bb = bet[col];
#pragma unroll
      for (int j = 0; j < 4; ++j) {
        const int row = row0 + hi * 4 + j;
        float y = (xx[cf][j] - mu[j]) * rs[j] * gm + bb;
        hf[(size_t)row * 256 + col]  = y;
        ybf[(size_t)row * 256 + col] = f2b_rne(y);
      }
    }
  }
}

// ---------------- phase D v2: weight-stationary, barrier-free per-wave tiles ----------------
__global__ __launch_bounds__(512, 2) void phase_d2(
    const unsigned short* __restrict__ hbf, const unsigned short* __restrict__ w1b,
    const float* __restrict__ b1, const float* __restrict__ lng, const float* __restrict__ lnb,
    const unsigned short* __restrict__ w2b, const float* __restrict__ b2,
    const float* __restrict__ w3, const float* __restrict__ b3,
    float* __restrict__ out) {
  __shared__ char sm[149504];
  const int tid = threadIdx.x, wid = tid >> 6, lane = tid & 63;
  const int r = lane & 15, hi = lane >> 4;
  const int sw = (r & 7) << 4;
  const int t = blockIdx.y;

  const unsigned short* w1t = w1b + (size_t)t * 32768;   // [128][256]
  const unsigned short* w2t = w2b + (size_t)t * 8192;    // [64][128]
#pragma unroll
  for (int i = 0; i < 8; ++i) {            // W1: 4096 16B chunks
    const int id = tid + i * 512;
    const int c = id >> 5, s = id & 31;
    bf16x8 v = *reinterpret_cast<const bf16x8*>(w1t + c * 256 + s * 8);
    *reinterpret_cast<bf16x8*>(sm + c * 512 + ((s * 16) ^ ((c & 7) << 4))) = v;
  }
#pragma unroll
  for (int i = 0; i < 2; ++i) {            // W2: 1024 16B chunks
    const int id = tid + i * 512;
    const int c = id >> 4, s = id & 15;
    bf16x8 v = *reinterpret_cast<const bf16x8*>(w2t + c * 128 + s * 8);
    *reinterpret_cast<bf16x8*>(sm + 65536 + c * 256 + ((s * 16) ^ ((c & 7) << 4))) = v;
  }
  {
    float v;
    if (tid < 128)      v = b1 [t * 128 + tid];
    else if (tid < 256) v = lng[t * 128 + tid - 128];
    else if (tid < 384) v = lnb[t * 128 + tid - 256];
    else if (tid < 448) v = b2 [t * 64  + tid - 384];
    else                v = w3 [t * 64  + tid - 448];
    reinterpret_cast<float*>(sm + 81920)[tid] = v;
  }
  __syncthreads();

  const float* cb1 = reinterpret_cast<const float*>(sm + 81920);
  const float* cg  = cb1 + 128;
  const float* cbe = cb1 + 256;
  const float* cb2 = cb1 + 384;
  const float* cw3 = cb1 + 448;
  char* t1w = sm + 83968 + wid * 8192;
  const float b3t = b3[t];
  const int token_b0 = blockIdx.x * 1024;

  for (int tile = 0; tile < 2; ++tile) {
    const int B0 = token_b0 + tile * 512 + wid * 64;

    f32x4 acc1[8][4] = {};
    bf16x8 bc[4], bn[4];
#pragma unroll
    for (int bf = 0; bf < 4; ++bf)
      bc[bf] = *reinterpret_cast<const bf16x8*>(hbf + (size_t)(B0 + bf * 16 + r) * 256 + hi * 8);
#pragma unroll
    for (int ks = 0; ks < 8; ++ks) {
      bf16x8 a[8];
#pragma unroll
      for (int cf = 0; cf < 8; ++cf)
        a[cf] = *reinterpret_cast<const bf16x8*>(sm + (cf * 16 + r) * 512 + ((ks * 64 + hi * 16) ^ sw));
      if (ks < 7) {
#pragma unroll
        for (int bf = 0; bf < 4; ++bf)
          bn[bf] = *reinterpret_cast<const bf16x8*>(hbf + (size_t)(B0 + bf * 16 + r) * 256 + (ks + 1) * 32 + hi * 8);
      }
      __builtin_amdgcn_s_setprio(1);
#pragma unroll
      for (int cf = 0; cf < 8; ++cf)
#pragma unroll
        for (int bf = 0; bf < 4; ++bf)
          acc1[cf][bf] = mfma16(a[cf], bc[bf], acc1[cf][bf]);
      __builtin_amdgcn_s_setprio(0);
#pragma unroll
      for (int bf = 0; bf < 4; ++bf) bc[bf] = bn[bf];
    }

#pragma unroll
    for (int cf = 0; cf < 8; ++cf) {
      f32x4 b1v = *reinterpret_cast<const f32x4*>(cb1 + cf * 16 + hi * 4);
#pragma unroll
      for (int bf = 0; bf < 4; ++bf) acc1[cf][bf] += b1v;
    }

    float mu[4], rsd[4];
#pragma unroll
    for (int bf = 0; bf < 4; ++bf) {
      float s = 0.f, s2 = 0.f;
#pragma unroll
      for (int cf = 0; cf < 8; ++cf)
#pragma unroll
        for (int j = 0; j < 4; ++j) { float v = acc1[cf][bf][j]; s += v; s2 += v * v; }
      s  += __shfl_xor(s, 16, 64);  s  += __shfl_xor(s, 32, 64);
      s2 += __shfl_xor(s2, 16, 64); s2 += __shfl_xor(s2, 32, 64);
      const float m = s * (1.f / 128.f);
      mu[bf] = m;
      rsd[bf] = rsqrtf(s2 * (1.f / 128.f) - m * m + 1e-5f);
    }

    f32x4 acc2[4][4] = {};
#pragma unroll
    for (int half = 0; half < 2; ++half) {
#pragma unroll
      for (int cf = 0; cf < 8; ++cf) {
        f32x4 gv = *reinterpret_cast<const f32x4*>(cg  + cf * 16 + hi * 4);
        f32x4 bv = *reinterpret_cast<const f32x4*>(cbe + cf * 16 + hi * 4);
#pragma unroll
        for (int bl = 0; bl < 2; ++bl) {
          const int bf = half * 2 + bl;
          unsigned o01, o23;
          {
            float y0 = fmaxf((acc1[cf][bf][0] - mu[bf]) * rsd[bf] * gv[0] + bv[0], 0.f);
            float y1 = fmaxf((acc1[cf][bf][1] - mu[bf]) * rsd[bf] * gv[1] + bv[1], 0.f);
            float y2 = fmaxf((acc1[cf][bf][2] - mu[bf]) * rsd[bf] * gv[2] + bv[2], 0.f);
            float y3 = fmaxf((acc1[cf][bf][3] - mu[bf]) * rsd[bf] * gv[3] + bv[3], 0.f);
            o01 = (unsigned)f2b_rne(y0) | ((unsigned)f2b_rne(y1) << 16);
            o23 = (unsigned)f2b_rne(y2) | ((unsigned)f2b_rne(y3) << 16);
          }
          uint2 pk; pk.x = o01; pk.y = o23;
          *reinterpret_cast<uint2*>(t1w + (bl * 16 + r) * 256 + ((cf * 32 + hi * 8) ^ sw)) = pk;
        }
      }
#pragma unroll
      for (int ks = 0; ks < 4; ++ks) {
        bf16x8 a2[4];
#pragma unroll
        for (int cf2 = 0; cf2 < 4; ++cf2)
          a2[cf2] = *reinterpret_cast<const bf16x8*>(sm + 65536 + (cf2 * 16 + r) * 256 + ((ks * 64 + hi * 16) ^ sw));
        __builtin_amdgcn_s_setprio(1);
#pragma unroll
        for (int bl = 0; bl < 2; ++bl) {
          bf16x8 bb = *reinterpret_cast<const bf16x8*>(t1w + (bl * 16 + r) * 256 + ((ks * 64 + hi * 16) ^ sw));
#pragma unroll
          for (int cf2 = 0; cf2 < 4; ++cf2)
            acc2[cf2][half * 2 + bl] = mfma16(a2[cf2], bb, acc2[cf2][half * 2 + bl]);
        }
        __builtin_amdgcn_s_setprio(0);
      }
    }

    float s[4] = {0.f, 0.f, 0.f, 0.f};
#pragma unroll
    for (int cf2 = 0; cf2 < 4; ++cf2) {
      f32x4 b2v = *reinterpret_cast<const f32x4*>(cb2 + cf2 * 16 + hi * 4);
      f32x4 w3v = *reinterpret_cast<const f32x4*>(cw3 + cf2 * 16 + hi * 4);
#pragma unroll
      for (int bf = 0; bf < 4; ++bf)
#pragma unroll
        for (int j = 0; j < 4; ++j)
          s[bf] += fmaxf(acc2[cf2][bf][j] + b2v[j], 0.f) * w3v[j];
    }
#pragma unroll
    for (int bf = 0; bf < 4; ++bf) {
      s[bf] += __shfl_xor(s[bf], 16, 64);
      s[bf] += __shfl_xor(s[bf], 32, 64);
      if (hi == 0) out[(size_t)(B0 + bf * 16 + r) * 424 + t] = s[bf] + b3t;
    }
  }
}

// ---------------- host launch ----------------
extern "C" void kernel_launch(void* const* d_in, const int* in_sizes, int n_in,
                              void* d_out, int out_size, void* d_ws, size_t ws_size,
                              hipStream_t stream) {
  const float* x     = (const float*)d_in[0];
  const float* projW = (const float*)d_in[1];
  const float* projb = (const float*)d_in[2];
  const float* aiW   = (const float*)d_in[3];
  const float* aib   = (const float*)d_in[4];
  const float* aoW   = (const float*)d_in[5];
  const float* aob   = (const float*)d_in[6];
  const float* lng   = (const float*)d_in[7];
  const float* lnbp  = (const float*)d_in[8];
  const float* f1W   = (const float*)d_in[9];
  const float* f1b   = (const float*)d_in[10];
  const float* f2W   = (const float*)d_in[11];
  const float* f2bp  = (const float*)d_in[12];
  const float* ciW   = (const float*)d_in[13];
  const float* cib   = (const float*)d_in[14];
  const float* coW   = (const float*)d_in[15];
  const float* cob   = (const float*)d_in[16];
  const float* tpW1  = (const float*)d_in[17];
  const float* tpb1  = (const float*)d_in[18];
  const float* tplng = (const float*)d_in[19];
  const float* tplnb = (const float*)d_in[20];
  const float* tpW2  = (const float*)d_in[21];
  const float* tpb2  = (const float*)d_in[22];
  const float* tpW3  = (const float*)d_in[23];
  const float* tpb3  = (const float*)d_in[24];
  float* out = (float*)d_out;

  char* ws = (char*)d_ws;
  size_t off = 0;
  auto alloc = [&](size_t n) { char* p = ws + off; off = (off + n + 255) & ~(size_t)255; return p; };
  unsigned short* xb   = (unsigned short*)alloc(4096ull * 512 * 2);
  unsigned short* pWb  = (unsigned short*)alloc(256ull * 512 * 2);
  unsigned short* f1Wb = (unsigned short*)alloc(6ull * 1024 * 256 * 2);
  unsigned short* f2Wb = (unsigned short*)alloc(6ull * 256 * 1024 * 2);
  unsigned short* W1b  = (unsigned short*)alloc(424ull * 128 * 256 * 2);
  unsigned short* W2b  = (unsigned short*)alloc(424ull * 64 * 128 * 2);
  unsigned short* wEff = (unsigned short*)alloc(7ull * 256 * 256 * 2);
  float*          bEff = (float*)alloc(7ull * 256 * 4);
  float*          hf   = (float*)alloc(4096ull * 256 * 4);
  unsigned short* hbf  = (unsigned short*)alloc(4096ull * 256 * 2);
  unsigned short* gbf  = (unsigned short*)alloc(4096ull * 1024 * 2);

  auto conv = [&](const float* s, unsigned short* d, size_t n) {
    int n4 = (int)(n >> 2);
    f2b_kernel<<<dim3((n4 + 255) / 256), dim3(256), 0, stream>>>(s, d, n4);
  };
  // weight composition (independent of conversions)
  compose_attn<<<dim3(16, 7), dim3(256), 0, stream>>>(aiW, aib, aoW, aob, ciW, cib, coW, cob, wEff, bEff);
  conv(x, xb, 4096ull * 512);
  conv(projW, pWb, 256ull * 512);
  conv(f1W, f1Wb, 6ull * 1024 * 256);
  conv(f2W, f2Wb, 6ull * 256 * 1024);
  conv(tpW1, W1b, 424ull * 128 * 256);
  conv(tpW2, W2b, 424ull * 64 * 128);

  dim3 blk(256);
  // proj: h = x @ proj_W^T + b  (EPI2, 32x128 tiles, grid 128x2)
  gemm_t2<2, 32, 512><<<dim3(128, 2), blk, 0, stream>>>(xb, pWb, projb, hf, hbf, nullptr, nullptr, 256);
  for (int i = 0; i < 6; ++i) {
    // h = LN(h + h @ W_eff^T + b_eff)   (EPI3, 16x256, grid 256)
    gemm_t2<3, 16, 256><<<dim3(256, 1), blk, 0, stream>>>(hbf, wEff + (size_t)i * 65536, bEff + i * 256,
                                                          hf, hbf, lng + i * 256, lnbp + i * 256, 256);
    // g = gelu(h @ W1^T + b1)           (EPI1, 32x128, grid 128x8)
    gemm_t2<1, 32, 256><<<dim3(128, 8), blk, 0, stream>>>(hbf, f1Wb + (size_t)i * 1024 * 256, f1b + i * 1024,
                                                          nullptr, gbf, nullptr, nullptr, 1024);
    // h = LN(h + g @ W2^T + b2)         (EPI3, 16x256, K=1024, grid 256)
    gemm_t2<3, 16, 1024><<<dim3(256, 1), blk, 0, stream>>>(gbf, f2Wb + (size_t)i * 256 * 1024, f2bp + i * 256,
                                                           hf, hbf, lng + i * 256, lnbp + i * 256, 256);
  }
  // cross: h = h + h @ Wc_eff^T + bc_eff  (EPI4, 32x128, grid 128x2)
  gemm_t2<4, 32, 256><<<dim3(128, 2), blk, 0, stream>>>(hbf, wEff + 6ull * 65536, bEff + 6 * 256,
                                                        hf, hbf, nullptr, nullptr, 256);

  // phase D: fused per-token MLP -> out (4096 x 424)
  phase_d2<<<dim3(4, 424), dim3(512), 0, stream>>>(hbf, W1b, tpb1, tplng, tplnb, W2b, tpb2, tpW3, tpb3, out);
}

// Round 5
// 559.110 us; speedup vs baseline: 1.1121x; 1.1121x over previous
//
#include <hip/hip_runtime.h>
#include <stdint.h>

// ---------------- types / helpers ----------------
using bf16x8 = __attribute__((ext_vector_type(8))) short;   // 8 x bf16 (4 VGPRs)
using f32x4  = __attribute__((ext_vector_type(4))) float;

__device__ __forceinline__ f32x4 mfma16(bf16x8 a, bf16x8 b, f32x4 c) {
  return __builtin_amdgcn_mfma_f32_16x16x32_bf16(a, b, c, 0, 0, 0);
}

__device__ __forceinline__ unsigned short f2b_rne(float f) {
  union { float f; unsigned u; } v; v.f = f;
  unsigned r = v.u + 0x7fffu + ((v.u >> 16) & 1u);
  return (unsigned short)(r >> 16);
}

// ---------------- fp32 -> bf16 conversion ----------------
__global__ void f2b_kernel(const float* __restrict__ s, unsigned short* __restrict__ d, int n4) {
  int i = blockIdx.x * 256 + threadIdx.x;
  if (i >= n4) return;
  float4 v = reinterpret_cast<const float4*>(s)[i];
  ushort4 o;
  o.x = f2b_rne(v.x); o.y = f2b_rne(v.y); o.z = f2b_rne(v.z); o.w = f2b_rne(v.w);
  reinterpret_cast<ushort4*>(d)[i] = o;
}

// ---------------- attn/cross weight composition (fp32): W_eff = Wo @ Wv, b_eff = Wo @ bv + bo ----
__global__ __launch_bounds__(256) void compose_attn(
    const float* __restrict__ aiW, const float* __restrict__ aib,
    const float* __restrict__ aoW, const float* __restrict__ aob,
    const float* __restrict__ ciW, const float* __restrict__ cib,
    const float* __restrict__ coW, const float* __restrict__ cob,
    unsigned short* __restrict__ wEff, float* __restrict__ bEff) {
  const int mat = blockIdx.y;
  const float* Wo = (mat < 6) ? aoW + (size_t)mat * 65536 : coW;
  const float* Wv = (mat < 6) ? aiW + (size_t)mat * 196608 + 131072 : ciW + 131072;
  const float* bv = (mat < 6) ? aib + mat * 768 + 512 : cib + 512;
  const float* bo = (mat < 6) ? aob + mat * 256 : cob;
  unsigned short* Wd = wEff + (size_t)mat * 65536;
  const int m = blockIdx.x * 16 + (threadIdx.x >> 4);
  const int k0 = (threadIdx.x & 15) * 16;
  float c[16] = {};
  for (int j = 0; j < 256; ++j) {
    const float a = Wo[m * 256 + j];
    const float* Br = Wv + j * 256 + k0;
#pragma unroll
    for (int kk = 0; kk < 16; ++kk) c[kk] = fmaf(a, Br[kk], c[kk]);
  }
#pragma unroll
  for (int kk = 0; kk < 16; ++kk) Wd[m * 256 + k0 + kk] = f2b_rne(c[kk]);
  if (blockIdx.x == 0) {
    const int mm = threadIdx.x;
    float s = 0.f;
    for (int j = 0; j < 256; ++j) s = fmaf(Wo[mm * 256 + j], bv[j], s);
    bEff[mat * 256 + mm] = s + bo[mm];
  }
}

// ---------------- streamed-W K-loop: A from LDS (row=r), W from global, depth-2 ring ----
template<int NCF, int K, int NK>
__device__ __forceinline__ void gemm_ws(const unsigned short* __restrict__ Wb,
                                        const char* __restrict__ smA_r,
                                        int hi16, int swz, f32x4 (&acc)[NCF]) {
  bf16x8 w[3][NCF];
#pragma unroll
  for (int p = 0; p < 2; ++p)
#pragma unroll
    for (int cf = 0; cf < NCF; ++cf)
      w[p][cf] = *reinterpret_cast<const bf16x8*>(Wb + (size_t)cf * 16 * K + p * 32);
#pragma unroll
  for (int ks = 0; ks < NK; ++ks) {
    const bf16x8 a = *reinterpret_cast<const bf16x8*>(smA_r + ((ks * 64 + hi16) ^ swz));
    if (ks + 2 < NK) {
#pragma unroll
      for (int cf = 0; cf < NCF; ++cf)
        w[(ks + 2) % 3][cf] = *reinterpret_cast<const bf16x8*>(Wb + (size_t)cf * 16 * K + (ks + 2) * 32);
    }
#pragma unroll
    for (int cf = 0; cf < NCF; ++cf)
      acc[cf] = mfma16(a, w[ks % 3][cf], acc[cf]);
  }
}

// ---------------- fused trunk: proj + 6 x (attn,LN,ff1,gelu,ff2,LN) + cross, ONE launch ----
// grid 256 blocks x 512 threads (8 waves). Block owns 16 rows for the whole trunk.
// h master: fp32 in registers, mapping (row = hi*4+j, col = wid*32 + cf*16 + r), cf in {0,1}
// hbuf: bf16 h [16][256] swizzled (MFMA A-operand); gbuf: bf16 g [16][1024] swizzled
__global__ __launch_bounds__(512, 2) void trunk_fused(
    const unsigned short* __restrict__ xb, const unsigned short* __restrict__ pWb,
    const float* __restrict__ projb,
    const unsigned short* __restrict__ wEff, const float* __restrict__ bEff,
    const unsigned short* __restrict__ f1Wb, const float* __restrict__ f1b,
    const unsigned short* __restrict__ f2Wb, const float* __restrict__ f2bp,
    const float* __restrict__ lng, const float* __restrict__ lnb,
    unsigned short* __restrict__ hbf) {
  __shared__ char hbuf[16 * 512];     // 8 KB
  __shared__ char gbuf[16 * 2048];    // 32 KB (also x-stage [16][512] @ stride 1024)
  __shared__ float red[2][16][8];
  const int tid = threadIdx.x, wid = tid >> 6, lane = tid & 63;
  const int r = lane & 15, hi = lane >> 4;
  const int swz = (r & 7) << 4, hi16 = hi * 16;
  const int row0 = blockIdx.x << 4;
  const int colb = wid * 32;

  // ---- stage x rows (16 x 512 bf16) into gbuf, stride 1024, swizzled ----
#pragma unroll
  for (int i = 0; i < 2; ++i) {
    const int id = tid + i * 512, row = id >> 6, c8 = id & 63;
    bf16x8 v = *reinterpret_cast<const bf16x8*>(xb + (size_t)(row0 + row) * 512 + c8 * 8);
    *reinterpret_cast<bf16x8*>(gbuf + row * 1024 + ((c8 * 16) ^ ((row & 7) << 4))) = v;
  }
  __syncthreads();

  f32x4 hreg[2];

  auto store_hb = [&]() {
#pragma unroll
    for (int cf = 0; cf < 2; ++cf) {
      const int cb = (colb + cf * 16 + r) * 2;
#pragma unroll
      for (int j = 0; j < 4; ++j) {
        const int row = hi * 4 + j;
        *reinterpret_cast<unsigned short*>(hbuf + row * 512 + (cb ^ ((row & 7) << 4))) =
            f2b_rne(hreg[cf][j]);
      }
    }
  };

  auto ln_apply = [&](float gm0, float gm1, float bb0, float bb1) {
    float sum[4], sq[4];
#pragma unroll
    for (int j = 0; j < 4; ++j) {
      const float v0 = hreg[0][j], v1 = hreg[1][j];
      sum[j] = v0 + v1; sq[j] = v0 * v0 + v1 * v1;
    }
#pragma unroll
    for (int m = 1; m < 16; m <<= 1)
#pragma unroll
      for (int j = 0; j < 4; ++j) {
        sum[j] += __shfl_xor(sum[j], m, 64);
        sq[j]  += __shfl_xor(sq[j],  m, 64);
      }
    if (r == 0)
#pragma unroll
      for (int j = 0; j < 4; ++j) {
        red[0][hi * 4 + j][wid] = sum[j];
        red[1][hi * 4 + j][wid] = sq[j];
      }
    __syncthreads();   // also guarantees all waves finished the preceding k-loop
#pragma unroll
    for (int j = 0; j < 4; ++j) {
      const int row = hi * 4 + j;
      f32x4 p0 = *reinterpret_cast<const f32x4*>(&red[0][row][0]);
      f32x4 p1 = *reinterpret_cast<const f32x4*>(&red[0][row][4]);
      f32x4 q0 = *reinterpret_cast<const f32x4*>(&red[1][row][0]);
      f32x4 q1 = *reinterpret_cast<const f32x4*>(&red[1][row][4]);
      const float ts = p0[0]+p0[1]+p0[2]+p0[3]+p1[0]+p1[1]+p1[2]+p1[3];
      const float tq = q0[0]+q0[1]+q0[2]+q0[3]+q1[0]+q1[1]+q1[2]+q1[3];
      const float mean = ts * (1.f / 256.f);
      const float rstd = rsqrtf(tq * (1.f / 256.f) - mean * mean + 1e-5f);
      hreg[0][j] = (hreg[0][j] - mean) * rstd * gm0 + bb0;
      hreg[1][j] = (hreg[1][j] - mean) * rstd * gm1 + bb1;
    }
  };

  // ---- proj: h = x @ pW^T + b (K=512) ----
  {
    f32x4 acc[2] = {};
    gemm_ws<2, 512, 16>(pWb + (size_t)(colb + r) * 512 + hi * 8, gbuf + r * 1024, hi16, swz, acc);
    const float bv0 = projb[colb + r], bv1 = projb[colb + 16 + r];
#pragma unroll
    for (int j = 0; j < 4; ++j) { hreg[0][j] = acc[0][j] + bv0; hreg[1][j] = acc[1][j] + bv1; }
  }
  store_hb();
  __syncthreads();

  for (int L = 0; L < 6; ++L) {
    const float gm0 = lng[L * 256 + colb + r],      gm1 = lng[L * 256 + colb + 16 + r];
    const float bb0 = lnb[L * 256 + colb + r],      bb1 = lnb[L * 256 + colb + 16 + r];
    // ---- attn (composed): h = LN(h + h @ W_eff^T + b_eff) ----
    {
      f32x4 acc[2] = {};
      gemm_ws<2, 256, 8>(wEff + (size_t)L * 65536 + (size_t)(colb + r) * 256 + hi * 8,
                         hbuf + r * 512, hi16, swz, acc);
      const float be0 = bEff[L * 256 + colb + r], be1 = bEff[L * 256 + colb + 16 + r];
#pragma unroll
      for (int j = 0; j < 4; ++j) { hreg[0][j] += acc[0][j] + be0; hreg[1][j] += acc[1][j] + be1; }
    }
    ln_apply(gm0, gm1, bb0, bb1);
    store_hb();
    __syncthreads();
    // ---- ff1: g = gelu(h @ W1^T + b1)  (out 1024 cols, wave owns 128) ----
    {
      f32x4 accf[8] = {};
      gemm_ws<8, 256, 8>(f1Wb + (size_t)L * 262144 + (size_t)(wid * 128 + r) * 256 + hi * 8,
                         hbuf + r * 512, hi16, swz, accf);
#pragma unroll
      for (int cf = 0; cf < 8; ++cf) {
        const int colw = wid * 128 + cf * 16 + r;
        const float bv = f1b[L * 1024 + colw];
        const int cb = colw * 2;
#pragma unroll
        for (int j = 0; j < 4; ++j) {
          float y = accf[cf][j] + bv;
          y = 0.5f * y * (1.f + erff(y * 0.70710678118654752f));
          const int row = hi * 4 + j;
          *reinterpret_cast<unsigned short*>(gbuf + row * 2048 + (cb ^ ((row & 7) << 4))) = f2b_rne(y);
        }
      }
    }
    __syncthreads();
    // ---- ff2: h = LN(h + g @ W2^T + b2)  (K=1024) ----
    {
      f32x4 acc[2] = {};
      gemm_ws<2, 1024, 32>(f2Wb + (size_t)L * 262144 + (size_t)(colb + r) * 1024 + hi * 8,
                           gbuf + r * 2048, hi16, swz, acc);
      const float be0 = f2bp[L * 256 + colb + r], be1 = f2bp[L * 256 + colb + 16 + r];
#pragma unroll
      for (int j = 0; j < 4; ++j) { hreg[0][j] += acc[0][j] + be0; hreg[1][j] += acc[1][j] + be1; }
    }
    ln_apply(gm0, gm1, bb0, bb1);
    store_hb();
    __syncthreads();
  }

  // ---- cross (composed, no LN): h = h + h @ Wc_eff^T + bc_eff ----
  {
    f32x4 acc[2] = {};
    gemm_ws<2, 256, 8>(wEff + 6ull * 65536 + (size_t)(colb + r) * 256 + hi * 8,
                       hbuf + r * 512, hi16, swz, acc);
    const float be0 = bEff[1536 + colb + r], be1 = bEff[1536 + colb + 16 + r];
#pragma unroll
    for (int j = 0; j < 4; ++j) { hreg[0][j] += acc[0][j] + be0; hreg[1][j] += acc[1][j] + be1; }
  }
#pragma unroll
  for (int cf = 0; cf < 2; ++cf)
#pragma unroll
    for (int j = 0; j < 4; ++j)
      hbf[(size_t)(row0 + hi * 4 + j) * 256 + colb + cf * 16 + r] = f2b_rne(hreg[cf][j]);
}

// ---------------- phase D v2: weight-stationary, barrier-free per-wave tiles (R3-exact) ----------------
__global__ __launch_bounds__(512, 2) void phase_d2(
    const unsigned short* __restrict__ hbf, const unsigned short* __restrict__ w1b,
    const float* __restrict__ b1, const float* __restrict__ lng, const float* __restrict__ lnb,
    const unsigned short* __restrict__ w2b, const float* __restrict__ b2,
    const float* __restrict__ w3, const float* __restrict__ b3,
    float* __restrict__ out) {
  __shared__ char sm[149504];
  const int tid = threadIdx.x, wid = tid >> 6, lane = tid & 63;
  const int r = lane & 15, hi = lane >> 4;
  const int sw = (r & 7) << 4;
  const int t = blockIdx.y;

  const unsigned short* w1t = w1b + (size_t)t * 32768;   // [128][256]
  const unsigned short* w2t = w2b + (size_t)t * 8192;    // [64][128]
#pragma unroll
  for (int i = 0; i < 8; ++i) {            // W1: 4096 16B chunks
    const int id = tid + i * 512;
    const int c = id >> 5, s = id & 31;
    bf16x8 v = *reinterpret_cast<const bf16x8*>(w1t + c * 256 + s * 8);
    *reinterpret_cast<bf16x8*>(sm + c * 512 + ((s * 16) ^ ((c & 7) << 4))) = v;
  }
#pragma unroll
  for (int i = 0; i < 2; ++i) {            // W2: 1024 16B chunks
    const int id = tid + i * 512;
    const int c = id >> 4, s = id & 15;
    bf16x8 v = *reinterpret_cast<const bf16x8*>(w2t + c * 128 + s * 8);
    *reinterpret_cast<bf16x8*>(sm + 65536 + c * 256 + ((s * 16) ^ ((c & 7) << 4))) = v;
  }
  {
    float v;
    if (tid < 128)      v = b1 [t * 128 + tid];
    else if (tid < 256) v = lng[t * 128 + tid - 128];
    else if (tid < 384) v = lnb[t * 128 + tid - 256];
    else if (tid < 448) v = b2 [t * 64  + tid - 384];
    else                v = w3 [t * 64  + tid - 448];
    reinterpret_cast<float*>(sm + 81920)[tid] = v;
  }
  __syncthreads();

  const float* cb1 = reinterpret_cast<const float*>(sm + 81920);
  const float* cg  = cb1 + 128;
  const float* cbe = cb1 + 256;
  const float* cb2 = cb1 + 384;
  const float* cw3 = cb1 + 448;
  char* t1w = sm + 83968 + wid * 8192;
  const float b3t = b3[t];
  const int token_b0 = blockIdx.x * 1024;

  for (int tile = 0; tile < 2; ++tile) {
    const int B0 = token_b0 + tile * 512 + wid * 64;

    f32x4 acc1[8][4] = {};
    bf16x8 bc[4], bn[4];
#pragma unroll
    for (int bf = 0; bf < 4; ++bf)
      bc[bf] = *reinterpret_cast<const bf16x8*>(hbf + (size_t)(B0 + bf * 16 + r) * 256 + hi * 8);
#pragma unroll
    for (int ks = 0; ks < 8; ++ks) {
      bf16x8 a[8];
#pragma unroll
      for (int cf = 0; cf < 8; ++cf)
        a[cf] = *reinterpret_cast<const bf16x8*>(sm + (cf * 16 + r) * 512 + ((ks * 64 + hi * 16) ^ sw));
      if (ks < 7) {
#pragma unroll
        for (int bf = 0; bf < 4; ++bf)
          bn[bf] = *reinterpret_cast<const bf16x8*>(hbf + (size_t)(B0 + bf * 16 + r) * 256 + (ks + 1) * 32 + hi * 8);
      }
#pragma unroll
      for (int cf = 0; cf < 8; ++cf)
#pragma unroll
        for (int bf = 0; bf < 4; ++bf)
          acc1[cf][bf] = mfma16(a[cf], bc[bf], acc1[cf][bf]);
#pragma unroll
      for (int bf = 0; bf < 4; ++bf) bc[bf] = bn[bf];
    }

#pragma unroll
    for (int cf = 0; cf < 8; ++cf) {
      f32x4 b1v = *reinterpret_cast<const f32x4*>(cb1 + cf * 16 + hi * 4);
#pragma unroll
      for (int bf = 0; bf < 4; ++bf) acc1[cf][bf] += b1v;
    }

    float mu[4], rsd[4];
#pragma unroll
    for (int bf = 0; bf < 4; ++bf) {
      float s = 0.f, s2 = 0.f;
#pragma unroll
      for (int cf = 0; cf < 8; ++cf)
#pragma unroll
        for (int j = 0; j < 4; ++j) { float v = acc1[cf][bf][j]; s += v; s2 += v * v; }
      s  += __shfl_xor(s, 16, 64);  s  += __shfl_xor(s, 32, 64);
      s2 += __shfl_xor(s2, 16, 64); s2 += __shfl_xor(s2, 32, 64);
      const float m = s * (1.f / 128.f);
      mu[bf] = m;
      rsd[bf] = rsqrtf(s2 * (1.f / 128.f) - m * m + 1e-5f);
    }

    f32x4 acc2[4][4] = {};
#pragma unroll
    for (int half = 0; half < 2; ++half) {
#pragma unroll
      for (int cf = 0; cf < 8; ++cf) {
        f32x4 gv = *reinterpret_cast<const f32x4*>(cg  + cf * 16 + hi * 4);
        f32x4 bv = *reinterpret_cast<const f32x4*>(cbe + cf * 16 + hi * 4);
#pragma unroll
        for (int bl = 0; bl < 2; ++bl) {
          const int bf = half * 2 + bl;
          unsigned o01, o23;
          {
            float y0 = fmaxf((acc1[cf][bf][0] - mu[bf]) * rsd[bf] * gv[0] + bv[0], 0.f);
            float y1 = fmaxf((acc1[cf][bf][1] - mu[bf]) * rsd[bf] * gv[1] + bv[1], 0.f);
            float y2 = fmaxf((acc1[cf][bf][2] - mu[bf]) * rsd[bf] * gv[2] + bv[2], 0.f);
            float y3 = fmaxf((acc1[cf][bf][3] - mu[bf]) * rsd[bf] * gv[3] + bv[3], 0.f);
            o01 = (unsigned)f2b_rne(y0) | ((unsigned)f2b_rne(y1) << 16);
            o23 = (unsigned)f2b_rne(y2) | ((unsigned)f2b_rne(y3) << 16);
          }
          uint2 pk; pk.x = o01; pk.y = o23;
          *reinterpret_cast<uint2*>(t1w + (bl * 16 + r) * 256 + ((cf * 32 + hi * 8) ^ sw)) = pk;
        }
      }
#pragma unroll
      for (int ks = 0; ks < 4; ++ks) {
        bf16x8 a2[4];
#pragma unroll
        for (int cf2 = 0; cf2 < 4; ++cf2)
          a2[cf2] = *reinterpret_cast<const bf16x8*>(sm + 65536 + (cf2 * 16 + r) * 256 + ((ks * 64 + hi * 16) ^ sw));
#pragma unroll
        for (int bl = 0; bl < 2; ++bl) {
          bf16x8 bb = *reinterpret_cast<const bf16x8*>(t1w + (bl * 16 + r) * 256 + ((ks * 64 + hi * 16) ^ sw));
#pragma unroll
          for (int cf2 = 0; cf2 < 4; ++cf2)
            acc2[cf2][half * 2 + bl] = mfma16(a2[cf2], bb, acc2[cf2][half * 2 + bl]);
        }
      }
    }

    float s[4] = {0.f, 0.f, 0.f, 0.f};
#pragma unroll
    for (int cf2 = 0; cf2 < 4; ++cf2) {
      f32x4 b2v = *reinterpret_cast<const f32x4*>(cb2 + cf2 * 16 + hi * 4);
      f32x4 w3v = *reinterpret_cast<const f32x4*>(cw3 + cf2 * 16 + hi * 4);
#pragma unroll
      for (int bf = 0; bf < 4; ++bf)
#pragma unroll
        for (int j = 0; j < 4; ++j)
          s[bf] += fmaxf(acc2[cf2][bf][j] + b2v[j], 0.f) * w3v[j];
    }
#pragma unroll
    for (int bf = 0; bf < 4; ++bf) {
      s[bf] += __shfl_xor(s[bf], 16, 64);
      s[bf] += __shfl_xor(s[bf], 32, 64);
      if (hi == 0) out[(size_t)(B0 + bf * 16 + r) * 424 + t] = s[bf] + b3t;
    }
  }
}

// ---------------- host launch ----------------
extern "C" void kernel_launch(void* const* d_in, const int* in_sizes, int n_in,
                              void* d_out, int out_size, void* d_ws, size_t ws_size,
                              hipStream_t stream) {
  const float* x     = (const float*)d_in[0];
  const float* projW = (const float*)d_in[1];
  const float* projb = (const float*)d_in[2];
  const float* aiW   = (const float*)d_in[3];
  const float* aib   = (const float*)d_in[4];
  const float* aoW   = (const float*)d_in[5];
  const float* aob   = (const float*)d_in[6];
  const float* lng   = (const float*)d_in[7];
  const float* lnbp  = (const float*)d_in[8];
  const float* f1W   = (const float*)d_in[9];
  const float* f1b   = (const float*)d_in[10];
  const float* f2W   = (const float*)d_in[11];
  const float* f2bp  = (const float*)d_in[12];
  const float* ciW   = (const float*)d_in[13];
  const float* cib   = (const float*)d_in[14];
  const float* coW   = (const float*)d_in[15];
  const float* cob   = (const float*)d_in[16];
  const float* tpW1  = (const float*)d_in[17];
  const float* tpb1  = (const float*)d_in[18];
  const float* tplng = (const float*)d_in[19];
  const float* tplnb = (const float*)d_in[20];
  const float* tpW2  = (const float*)d_in[21];
  const float* tpb2  = (const float*)d_in[22];
  const float* tpW3  = (const float*)d_in[23];
  const float* tpb3  = (const float*)d_in[24];
  float* out = (float*)d_out;

  char* ws = (char*)d_ws;
  size_t off = 0;
  auto alloc = [&](size_t n) { char* p = ws + off; off = (off + n + 255) & ~(size_t)255; return p; };
  unsigned short* xb   = (unsigned short*)alloc(4096ull * 512 * 2);
  unsigned short* pWb  = (unsigned short*)alloc(256ull * 512 * 2);
  unsigned short* f1Wb = (unsigned short*)alloc(6ull * 1024 * 256 * 2);
  unsigned short* f2Wb = (unsigned short*)alloc(6ull * 256 * 1024 * 2);
  unsigned short* W1b  = (unsigned short*)alloc(424ull * 128 * 256 * 2);
  unsigned short* W2b  = (unsigned short*)alloc(424ull * 64 * 128 * 2);
  unsigned short* wEff = (unsigned short*)alloc(7ull * 256 * 256 * 2);
  float*          bEff = (float*)alloc(7ull * 256 * 4);
  unsigned short* hbf  = (unsigned short*)alloc(4096ull * 256 * 2);

  auto conv = [&](const float* s, unsigned short* d, size_t n) {
    int n4 = (int)(n >> 2);
    f2b_kernel<<<dim3((n4 + 255) / 256), dim3(256), 0, stream>>>(s, d, n4);
  };
  compose_attn<<<dim3(16, 7), dim3(256), 0, stream>>>(aiW, aib, aoW, aob, ciW, cib, coW, cob, wEff, bEff);
  conv(x, xb, 4096ull * 512);
  conv(projW, pWb, 256ull * 512);
  conv(f1W, f1Wb, 6ull * 1024 * 256);
  conv(f2W, f2Wb, 6ull * 256 * 1024);
  conv(tpW1, W1b, 424ull * 128 * 256);
  conv(tpW2, W2b, 424ull * 64 * 128);

  // whole trunk in one launch: 256 blocks x 16 rows
  trunk_fused<<<dim3(256), dim3(512), 0, stream>>>(
      xb, pWb, projb, wEff, bEff, f1Wb, f1b, f2Wb, f2bp, lng, lnbp, hbf);

  // phase D: fused per-token MLP -> out (4096 x 424)
  phase_d2<<<dim3(4, 424), dim3(512), 0, stream>>>(hbf, W1b, tpb1, tplng, tplnb, W2b, tpb2, tpW3, tpb3, out);
}

// Round 6
// 523.624 us; speedup vs baseline: 1.1874x; 1.0678x over previous
//
#include <hip/hip_runtime.h>
#include <stdint.h>
#include <utility>
#include <type_traits>

// ---------------- types / helpers ----------------
using bf16x8 = __attribute__((ext_vector_type(8))) short;   // 8 x bf16 (4 VGPRs)
using f32x4  = __attribute__((ext_vector_type(4))) float;

__device__ __forceinline__ f32x4 mfma16(bf16x8 a, bf16x8 b, f32x4 c) {
  return __builtin_amdgcn_mfma_f32_16x16x32_bf16(a, b, c, 0, 0, 0);
}

__device__ __forceinline__ unsigned short f2b_rne(float f) {
  union { float f; unsigned u; } v; v.f = f;
  unsigned r = v.u + 0x7fffu + ((v.u >> 16) & 1u);
  return (unsigned short)(r >> 16);
}

__device__ __forceinline__ void gload16(const void* g, void* l) {
  __builtin_amdgcn_global_load_lds(
      (const __attribute__((address_space(1))) void*)g,
      (__attribute__((address_space(3))) void*)l, 16, 0, 0);
}

template<int N> __device__ __forceinline__ void vmwait() {
  if constexpr (N <= 0)      asm volatile("s_waitcnt vmcnt(0)" ::: "memory");
  else if constexpr (N == 4) asm volatile("s_waitcnt vmcnt(4)" ::: "memory");
  else                       asm volatile("s_waitcnt vmcnt(8)" ::: "memory");
}

template<class F, int... Is>
__device__ __forceinline__ void sfor_impl(F&& f, std::integer_sequence<int, Is...>) {
  (f(std::integral_constant<int, Is>{}), ...);
}
template<int N, class F>
__device__ __forceinline__ void sfor(F&& f) {
  sfor_impl(static_cast<F&&>(f), std::make_integer_sequence<int, N>{});
}

// Stage one 16-col x 128-k tile (4 KB) of W[cols][K] into a wave-private LDS slot.
// Global source is pre-swizzled (XOR (col&7)<<4 within each col's 256B slice) so the
// linear LDS dest reads back bank-conflict-free with the same XOR on the read side.
__device__ __forceinline__ void stage_tile(const unsigned short* __restrict__ W, int K,
                                           int col0, int kt, char* slot, int lane) {
#pragma unroll
  for (int i = 0; i < 4; ++i) {
    const int chunk = i * 64 + lane;
    const int ci = chunk >> 4, kc = chunk & 15;
    const unsigned short* src = W + (size_t)(col0 + ci) * K + kt * 128
                                + (((kc * 16) ^ ((ci & 7) << 4)) >> 1);
    gload16(src, slot + i * 1024);   // lane's 16B lands at slot + i*1024 + lane*16
  }
}

// Per-wave pipelined GEMM: acc[cg] (+)= A[16 x K] @ W[(c0..c0+NCG*16) x K]^T
// A in LDS (row stride AS bytes, XOR-swizzled); W streamed from global via LDS ring
// (3 slots x 4KB, wave-private), 2 tiles in flight, steady-state vmcnt(4).
template<int NCG, int NKT, int AS, int K>
__device__ __forceinline__ void gemm_pipe(const unsigned short* __restrict__ W, int c0,
                                          const char* __restrict__ abuf,
                                          char* __restrict__ ring, int lane,
                                          f32x4 (&acc)[NCG]) {
  const int r = lane & 15, hi16 = (lane >> 4) << 4;
  const int swz = (r & 7) << 4;
  constexpr int TILES = NCG * NKT;   // tile t = (kt, cg) = (t / NCG, t % NCG)
  stage_tile(W, K, c0, 0, ring, lane);
  if constexpr (TILES > 1)
    stage_tile(W, K, c0 + (1 % NCG) * 16, 1 / NCG, ring + 4096, lane);
  bf16x8 areg[4];
  sfor<TILES>([&](auto tc) {
    constexpr int t = tc.value;
    constexpr int kt = t / NCG, cg = t % NCG;
    vmwait<((t + 2 <= TILES) ? 4 : 0)>();
    __builtin_amdgcn_sched_barrier(0);
    if constexpr (t + 2 < TILES) {
      constexpr int t2 = t + 2;
      stage_tile(W, K, c0 + (t2 % NCG) * 16, t2 / NCG, ring + (t2 % 3) * 4096, lane);
    }
    const char* slot = ring + (t % 3) * 4096;
#pragma unroll
    for (int ksl = 0; ksl < 4; ++ksl) {
      if constexpr (cg == 0)
        areg[ksl] = *reinterpret_cast<const bf16x8*>(
            abuf + r * AS + ((kt * 256 + ksl * 64 + hi16) ^ swz));
      const bf16x8 b = *reinterpret_cast<const bf16x8*>(
          slot + r * 256 + ((ksl * 64 + hi16) ^ swz));
      acc[cg] = mfma16(areg[ksl], b, acc[cg]);
    }
  });
}

// ---------------- fp32 -> bf16 conversion ----------------
__global__ void f2b_kernel(const float* __restrict__ s, unsigned short* __restrict__ d, int n4) {
  int i = blockIdx.x * 256 + threadIdx.x;
  if (i >= n4) return;
  float4 v = reinterpret_cast<const float4*>(s)[i];
  ushort4 o;
  o.x = f2b_rne(v.x); o.y = f2b_rne(v.y); o.z = f2b_rne(v.z); o.w = f2b_rne(v.w);
  reinterpret_cast<ushort4*>(d)[i] = o;
}

// ---------------- attn/cross weight composition (fp32): W_eff = Wo @ Wv, b_eff = Wo @ bv + bo ----
__global__ __launch_bounds__(256) void compose_attn(
    const float* __restrict__ aiW, const float* __restrict__ aib,
    const float* __restrict__ aoW, const float* __restrict__ aob,
    const float* __restrict__ ciW, const float* __restrict__ cib,
    const float* __restrict__ coW, const float* __restrict__ cob,
    unsigned short* __restrict__ wEff, float* __restrict__ bEff) {
  const int mat = blockIdx.y;
  const float* Wo = (mat < 6) ? aoW + (size_t)mat * 65536 : coW;
  const float* Wv = (mat < 6) ? aiW + (size_t)mat * 196608 + 131072 : ciW + 131072;
  const float* bv = (mat < 6) ? aib + mat * 768 + 512 : cib + 512;
  const float* bo = (mat < 6) ? aob + mat * 256 : cob;
  unsigned short* Wd = wEff + (size_t)mat * 65536;
  const int m = blockIdx.x * 16 + (threadIdx.x >> 4);
  const int k0 = (threadIdx.x & 15) * 16;
  float c[16] = {};
  for (int j = 0; j < 256; ++j) {
    const float a = Wo[m * 256 + j];
    const float* Br = Wv + j * 256 + k0;
#pragma unroll
    for (int kk = 0; kk < 16; ++kk) c[kk] = fmaf(a, Br[kk], c[kk]);
  }
#pragma unroll
  for (int kk = 0; kk < 16; ++kk) Wd[m * 256 + k0 + kk] = f2b_rne(c[kk]);
  if (blockIdx.x == 0) {
    const int mm = threadIdx.x;
    float s = 0.f;
    for (int j = 0; j < 256; ++j) s = fmaf(Wo[mm * 256 + j], bv[j], s);
    bEff[mat * 256 + mm] = s + bo[mm];
  }
}

// ---------------- fused trunk: proj + 6 x (attn,LN,ff1,gelu,ff2,LN) + cross, ONE launch ----
// grid 256 x 512 threads (8 waves). Block owns 16 rows; weights streamed via per-wave
// LDS rings (global_load_lds + counted vmcnt). h master fp32 in registers.
__global__ __launch_bounds__(512, 2) void trunk_fused(
    const unsigned short* __restrict__ xb, const unsigned short* __restrict__ pWb,
    const float* __restrict__ projb,
    const unsigned short* __restrict__ wEff, const float* __restrict__ bEff,
    const unsigned short* __restrict__ f1Wb, const float* __restrict__ f1b,
    const unsigned short* __restrict__ f2Wb, const float* __restrict__ f2bp,
    const float* __restrict__ lng, const float* __restrict__ lnb,
    unsigned short* __restrict__ hbf) {
  __shared__ char hbuf[16 * 512];        // h bf16 [16][256] swizzled (8 KB)
  __shared__ char gbuf[16 * 2048];       // g bf16 [16][1024] swizzled (32 KB); x-stage [16][512] @ stride 1024
  __shared__ char ringbuf[8 * 12288];    // per-wave 3 x 4KB W-tile rings (96 KB)
  __shared__ float red[2][16][8];
  const int tid = threadIdx.x, wid = tid >> 6, lane = tid & 63;
  const int r = lane & 15, hi = lane >> 4;
  const int swz = (r & 7) << 4;
  const int row0 = blockIdx.x << 4;
  const int colb = wid * 32;
  char* ring = ringbuf + wid * 12288;

  // ---- stage x rows (16 x 512 bf16) into gbuf, stride 1024, swizzled ----
#pragma unroll
  for (int i = 0; i < 2; ++i) {
    const int id = tid + i * 512, row = id >> 6, c8 = id & 63;
    bf16x8 v = *reinterpret_cast<const bf16x8*>(xb + (size_t)(row0 + row) * 512 + c8 * 8);
    *reinterpret_cast<bf16x8*>(gbuf + row * 1024 + ((c8 * 16) ^ ((row & 7) << 4))) = v;
  }
  __syncthreads();

  f32x4 hreg[2];

  auto store_hb = [&]() {
#pragma unroll
    for (int cf = 0; cf < 2; ++cf) {
      const int cb = (colb + cf * 16 + r) * 2;
#pragma unroll
      for (int j = 0; j < 4; ++j) {
        const int row = hi * 4 + j;
        *reinterpret_cast<unsigned short*>(hbuf + row * 512 + (cb ^ ((row & 7) << 4))) =
            f2b_rne(hreg[cf][j]);
      }
    }
  };

  auto ln_apply = [&](float gm0, float gm1, float bb0, float bb1) {
    float sum[4], sq[4];
#pragma unroll
    for (int j = 0; j < 4; ++j) {
      const float v0 = hreg[0][j], v1 = hreg[1][j];
      sum[j] = v0 + v1; sq[j] = v0 * v0 + v1 * v1;
    }
#pragma unroll
    for (int m = 1; m < 16; m <<= 1)
#pragma unroll
      for (int j = 0; j < 4; ++j) {
        sum[j] += __shfl_xor(sum[j], m, 64);
        sq[j]  += __shfl_xor(sq[j],  m, 64);
      }
    if (r == 0)
#pragma unroll
      for (int j = 0; j < 4; ++j) {
        red[0][hi * 4 + j][wid] = sum[j];
        red[1][hi * 4 + j][wid] = sq[j];
      }
    __syncthreads();
#pragma unroll
    for (int j = 0; j < 4; ++j) {
      const int row = hi * 4 + j;
      f32x4 p0 = *reinterpret_cast<const f32x4*>(&red[0][row][0]);
      f32x4 p1 = *reinterpret_cast<const f32x4*>(&red[0][row][4]);
      f32x4 q0 = *reinterpret_cast<const f32x4*>(&red[1][row][0]);
      f32x4 q1 = *reinterpret_cast<const f32x4*>(&red[1][row][4]);
      const float ts = p0[0]+p0[1]+p0[2]+p0[3]+p1[0]+p1[1]+p1[2]+p1[3];
      const float tq = q0[0]+q0[1]+q0[2]+q0[3]+q1[0]+q1[1]+q1[2]+q1[3];
      const float mean = ts * (1.f / 256.f);
      const float rstd = rsqrtf(tq * (1.f / 256.f) - mean * mean + 1e-5f);
      hreg[0][j] = (hreg[0][j] - mean) * rstd * gm0 + bb0;
      hreg[1][j] = (hreg[1][j] - mean) * rstd * gm1 + bb1;
    }
  };

  // ---- proj: h = x @ pW^T + b (K=512, A=x in gbuf stride 1024) ----
  {
    f32x4 acc[2] = {};
    gemm_pipe<2, 4, 1024, 512>(pWb, colb, gbuf, ring, lane, acc);
    const float bv0 = projb[colb + r], bv1 = projb[colb + 16 + r];
#pragma unroll
    for (int j = 0; j < 4; ++j) { hreg[0][j] = acc[0][j] + bv0; hreg[1][j] = acc[1][j] + bv1; }
  }
  store_hb();
  __syncthreads();

  for (int L = 0; L < 6; ++L) {
    const float gm0 = lng[L * 256 + colb + r],      gm1 = lng[L * 256 + colb + 16 + r];
    const float bb0 = lnb[L * 256 + colb + r],      bb1 = lnb[L * 256 + colb + 16 + r];
    // ---- attn (composed): h = LN(h + h @ W_eff^T + b_eff) ----
    {
      f32x4 acc[2] = {};
      gemm_pipe<2, 2, 512, 256>(wEff + (size_t)L * 65536, colb, hbuf, ring, lane, acc);
      const float be0 = bEff[L * 256 + colb + r], be1 = bEff[L * 256 + colb + 16 + r];
#pragma unroll
      for (int j = 0; j < 4; ++j) { hreg[0][j] += acc[0][j] + be0; hreg[1][j] += acc[1][j] + be1; }
    }
    ln_apply(gm0, gm1, bb0, bb1);
    store_hb();
    __syncthreads();
    // ---- ff1: g = gelu(h @ W1^T + b1)  (1024 out cols, wave owns 128) ----
    {
      f32x4 accf[8] = {};
      gemm_pipe<8, 2, 512, 256>(f1Wb + (size_t)L * 262144, wid * 128, hbuf, ring, lane, accf);
#pragma unroll
      for (int cf = 0; cf < 8; ++cf) {
        const int colw = wid * 128 + cf * 16 + r;
        const float bv = f1b[L * 1024 + colw];
        const int cb = colw * 2;
#pragma unroll
        for (int j = 0; j < 4; ++j) {
          float y = accf[cf][j] + bv;
          y = 0.5f * y * (1.f + erff(y * 0.70710678118654752f));
          const int row = hi * 4 + j;
          *reinterpret_cast<unsigned short*>(gbuf + row * 2048 + (cb ^ ((row & 7) << 4))) = f2b_rne(y);
        }
      }
    }
    __syncthreads();
    // ---- ff2: h = LN(h + g @ W2^T + b2)  (K=1024, A=g in gbuf stride 2048) ----
    {
      f32x4 acc[2] = {};
      gemm_pipe<2, 8, 2048, 1024>(f2Wb + (size_t)L * 262144, colb, gbuf, ring, lane, acc);
      const float be0 = f2bp[L * 256 + colb + r], be1 = f2bp[L * 256 + colb + 16 + r];
#pragma unroll
      for (int j = 0; j < 4; ++j) { hreg[0][j] += acc[0][j] + be0; hreg[1][j] += acc[1][j] + be1; }
    }
    ln_apply(gm0, gm1, bb0, bb1);
    store_hb();
    __syncthreads();
  }

  // ---- cross (composed, no LN): h = h + h @ Wc_eff^T + bc_eff ----
  {
    f32x4 acc[2] = {};
    gemm_pipe<2, 2, 512, 256>(wEff + 6ull * 65536, colb, hbuf, ring, lane, acc);
    const float be0 = bEff[1536 + colb + r], be1 = bEff[1536 + colb + 16 + r];
#pragma unroll
    for (int j = 0; j < 4; ++j) { hreg[0][j] += acc[0][j] + be0; hreg[1][j] += acc[1][j] + be1; }
  }
#pragma unroll
  for (int cf = 0; cf < 2; ++cf)
#pragma unroll
    for (int j = 0; j < 4; ++j)
      hbf[(size_t)(row0 + hi * 4 + j) * 256 + colb + cf * 16 + r] = f2b_rne(hreg[cf][j]);
}

// ---------------- phase D v2: weight-stationary, barrier-free per-wave tiles (R3-exact) ----------------
__global__ __launch_bounds__(512, 2) void phase_d2(
    const unsigned short* __restrict__ hbf, const unsigned short* __restrict__ w1b,
    const float* __restrict__ b1, const float* __restrict__ lng, const float* __restrict__ lnb,
    const unsigned short* __restrict__ w2b, const float* __restrict__ b2,
    const float* __restrict__ w3, const float* __restrict__ b3,
    float* __restrict__ out) {
  __shared__ char sm[149504];
  const int tid = threadIdx.x, wid = tid >> 6, lane = tid & 63;
  const int r = lane & 15, hi = lane >> 4;
  const int sw = (r & 7) << 4;
  const int t = blockIdx.y;

  const unsigned short* w1t = w1b + (size_t)t * 32768;   // [128][256]
  const unsigned short* w2t = w2b + (size_t)t * 8192;    // [64][128]
#pragma unroll
  for (int i = 0; i < 8; ++i) {            // W1: 4096 16B chunks
    const int id = tid + i * 512;
    const int c = id >> 5, s = id & 31;
    bf16x8 v = *reinterpret_cast<const bf16x8*>(w1t + c * 256 + s * 8);
    *reinterpret_cast<bf16x8*>(sm + c * 512 + ((s * 16) ^ ((c & 7) << 4))) = v;
  }
#pragma unroll
  for (int i = 0; i < 2; ++i) {            // W2: 1024 16B chunks
    const int id = tid + i * 512;
    const int c = id >> 4, s = id & 15;
    bf16x8 v = *reinterpret_cast<const bf16x8*>(w2t + c * 128 + s * 8);
    *reinterpret_cast<bf16x8*>(sm + 65536 + c * 256 + ((s * 16) ^ ((c & 7) << 4))) = v;
  }
  {
    float v;
    if (tid < 128)      v = b1 [t * 128 + tid];
    else if (tid < 256) v = lng[t * 128 + tid - 128];
    else if (tid < 384) v = lnb[t * 128 + tid - 256];
    else if (tid < 448) v = b2 [t * 64  + tid - 384];
    else                v = w3 [t * 64  + tid - 448];
    reinterpret_cast<float*>(sm + 81920)[tid] = v;
  }
  __syncthreads();

  const float* cb1 = reinterpret_cast<const float*>(sm + 81920);
  const float* cg  = cb1 + 128;
  const float* cbe = cb1 + 256;
  const float* cb2 = cb1 + 384;
  const float* cw3 = cb1 + 448;
  char* t1w = sm + 83968 + wid * 8192;
  const float b3t = b3[t];
  const int token_b0 = blockIdx.x * 1024;

  for (int tile = 0; tile < 2; ++tile) {
    const int B0 = token_b0 + tile * 512 + wid * 64;

    f32x4 acc1[8][4] = {};
    bf16x8 bc[4], bn[4];
#pragma unroll
    for (int bf = 0; bf < 4; ++bf)
      bc[bf] = *reinterpret_cast<const bf16x8*>(hbf + (size_t)(B0 + bf * 16 + r) * 256 + hi * 8);
#pragma unroll
    for (int ks = 0; ks < 8; ++ks) {
      bf16x8 a[8];
#pragma unroll
      for (int cf = 0; cf < 8; ++cf)
        a[cf] = *reinterpret_cast<const bf16x8*>(sm + (cf * 16 + r) * 512 + ((ks * 64 + hi * 16) ^ sw));
      if (ks < 7) {
#pragma unroll
        for (int bf = 0; bf < 4; ++bf)
          bn[bf] = *reinterpret_cast<const bf16x8*>(hbf + (size_t)(B0 + bf * 16 + r) * 256 + (ks + 1) * 32 + hi * 8);
      }
#pragma unroll
      for (int cf = 0; cf < 8; ++cf)
#pragma unroll
        for (int bf = 0; bf < 4; ++bf)
          acc1[cf][bf] = mfma16(a[cf], bc[bf], acc1[cf][bf]);
#pragma unroll
      for (int bf = 0; bf < 4; ++bf) bc[bf] = bn[bf];
    }

#pragma unroll
    for (int cf = 0; cf < 8; ++cf) {
      f32x4 b1v = *reinterpret_cast<const f32x4*>(cb1 + cf * 16 + hi * 4);
#pragma unroll
      for (int bf = 0; bf < 4; ++bf) acc1[cf][bf] += b1v;
    }

    float mu[4], rsd[4];
#pragma unroll
    for (int bf = 0; bf < 4; ++bf) {
      float s = 0.f, s2 = 0.f;
#pragma unroll
      for (int cf = 0; cf < 8; ++cf)
#pragma unroll
        for (int j = 0; j < 4; ++j) { float v = acc1[cf][bf][j]; s += v; s2 += v * v; }
      s  += __shfl_xor(s, 16, 64);  s  += __shfl_xor(s, 32, 64);
      s2 += __shfl_xor(s2, 16, 64); s2 += __shfl_xor(s2, 32, 64);
      const float m = s * (1.f / 128.f);
      mu[bf] = m;
      rsd[bf] = rsqrtf(s2 * (1.f / 128.f) - m * m + 1e-5f);
    }

    f32x4 acc2[4][4] = {};
#pragma unroll
    for (int half = 0; half < 2; ++half) {
#pragma unroll
      for (int cf = 0; cf < 8; ++cf) {
        f32x4 gv = *reinterpret_cast<const f32x4*>(cg  + cf * 16 + hi * 4);
        f32x4 bv = *reinterpret_cast<const f32x4*>(cbe + cf * 16 + hi * 4);
#pragma unroll
        for (int bl = 0; bl < 2; ++bl) {
          const int bf = half * 2 + bl;
          unsigned o01, o23;
          {
            float y0 = fmaxf((acc1[cf][bf][0] - mu[bf]) * rsd[bf] * gv[0] + bv[0], 0.f);
            float y1 = fmaxf((acc1[cf][bf][1] - mu[bf]) * rsd[bf] * gv[1] + bv[1], 0.f);
            float y2 = fmaxf((acc1[cf][bf][2] - mu[bf]) * rsd[bf] * gv[2] + bv[2], 0.f);
            float y3 = fmaxf((acc1[cf][bf][3] - mu[bf]) * rsd[bf] * gv[3] + bv[3], 0.f);
            o01 = (unsigned)f2b_rne(y0) | ((unsigned)f2b_rne(y1) << 16);
            o23 = (unsigned)f2b_rne(y2) | ((unsigned)f2b_rne(y3) << 16);
          }
          uint2 pk; pk.x = o01; pk.y = o23;
          *reinterpret_cast<uint2*>(t1w + (bl * 16 + r) * 256 + ((cf * 32 + hi * 8) ^ sw)) = pk;
        }
      }
#pragma unroll
      for (int ks = 0; ks < 4; ++ks) {
        bf16x8 a2[4];
#pragma unroll
        for (int cf2 = 0; cf2 < 4; ++cf2)
          a2[cf2] = *reinterpret_cast<const bf16x8*>(sm + 65536 + (cf2 * 16 + r) * 256 + ((ks * 64 + hi * 16) ^ sw));
#pragma unroll
        for (int bl = 0; bl < 2; ++bl) {
          bf16x8 bb = *reinterpret_cast<const bf16x8*>(t1w + (bl * 16 + r) * 256 + ((ks * 64 + hi * 16) ^ sw));
#pragma unroll
          for (int cf2 = 0; cf2 < 4; ++cf2)
            acc2[cf2][half * 2 + bl] = mfma16(a2[cf2], bb, acc2[cf2][half * 2 + bl]);
        }
      }
    }

    float s[4] = {0.f, 0.f, 0.f, 0.f};
#pragma unroll
    for (int cf2 = 0; cf2 < 4; ++cf2) {
      f32x4 b2v = *reinterpret_cast<const f32x4*>(cb2 + cf2 * 16 + hi * 4);
      f32x4 w3v = *reinterpret_cast<const f32x4*>(cw3 + cf2 * 16 + hi * 4);
#pragma unroll
      for (int bf = 0; bf < 4; ++bf)
#pragma unroll
        for (int j = 0; j < 4; ++j)
          s[bf] += fmaxf(acc2[cf2][bf][j] + b2v[j], 0.f) * w3v[j];
    }
#pragma unroll
    for (int bf = 0; bf < 4; ++bf) {
      s[bf] += __shfl_xor(s[bf], 16, 64);
      s[bf] += __shfl_xor(s[bf], 32, 64);
      if (hi == 0) out[(size_t)(B0 + bf * 16 + r) * 424 + t] = s[bf] + b3t;
    }
  }
}

// ---------------- host launch ----------------
extern "C" void kernel_launch(void* const* d_in, const int* in_sizes, int n_in,
                              void* d_out, int out_size, void* d_ws, size_t ws_size,
                              hipStream_t stream) {
  const float* x     = (const float*)d_in[0];
  const float* projW = (const float*)d_in[1];
  const float* projb = (const float*)d_in[2];
  const float* aiW   = (const float*)d_in[3];
  const float* aib   = (const float*)d_in[4];
  const float* aoW   = (const float*)d_in[5];
  const float* aob   = (const float*)d_in[6];
  const float* lng   = (const float*)d_in[7];
  const float* lnbp  = (const float*)d_in[8];
  const float* f1W   = (const float*)d_in[9];
  const float* f1b   = (const float*)d_in[10];
  const float* f2W   = (const float*)d_in[11];
  const float* f2bp  = (const float*)d_in[12];
  const float* ciW   = (const float*)d_in[13];
  const float* cib   = (const float*)d_in[14];
  const float* coW   = (const float*)d_in[15];
  const float* cob   = (const float*)d_in[16];
  const float* tpW1  = (const float*)d_in[17];
  const float* tpb1  = (const float*)d_in[18];
  const float* tplng = (const float*)d_in[19];
  const float* tplnb = (const float*)d_in[20];
  const float* tpW2  = (const float*)d_in[21];
  const float* tpb2  = (const float*)d_in[22];
  const float* tpW3  = (const float*)d_in[23];
  const float* tpb3  = (const float*)d_in[24];
  float* out = (float*)d_out;

  char* ws = (char*)d_ws;
  size_t off = 0;
  auto alloc = [&](size_t n) { char* p = ws + off; off = (off + n + 255) & ~(size_t)255; return p; };
  unsigned short* xb   = (unsigned short*)alloc(4096ull * 512 * 2);
  unsigned short* pWb  = (unsigned short*)alloc(256ull * 512 * 2);
  unsigned short* f1Wb = (unsigned short*)alloc(6ull * 1024 * 256 * 2);
  unsigned short* f2Wb = (unsigned short*)alloc(6ull * 256 * 1024 * 2);
  unsigned short* W1b  = (unsigned short*)alloc(424ull * 128 * 256 * 2);
  unsigned short* W2b  = (unsigned short*)alloc(424ull * 64 * 128 * 2);
  unsigned short* wEff = (unsigned short*)alloc(7ull * 256 * 256 * 2);
  float*          bEff = (float*)alloc(7ull * 256 * 4);
  unsigned short* hbf  = (unsigned short*)alloc(4096ull * 256 * 2);

  auto conv = [&](const float* s, unsigned short* d, size_t n) {
    int n4 = (int)(n >> 2);
    f2b_kernel<<<dim3((n4 + 255) / 256), dim3(256), 0, stream>>>(s, d, n4);
  };
  compose_attn<<<dim3(16, 7), dim3(256), 0, stream>>>(aiW, aib, aoW, aob, ciW, cib, coW, cob, wEff, bEff);
  conv(x, xb, 4096ull * 512);
  conv(projW, pWb, 256ull * 512);
  conv(f1W, f1Wb, 6ull * 1024 * 256);
  conv(f2W, f2Wb, 6ull * 256 * 1024);
  conv(tpW1, W1b, 424ull * 128 * 256);
  conv(tpW2, W2b, 424ull * 64 * 128);

  // whole trunk in one launch: 256 blocks x 16 rows
  trunk_fused<<<dim3(256), dim3(512), 0, stream>>>(
      xb, pWb, projb, wEff, bEff, f1Wb, f1b, f2Wb, f2bp, lng, lnbp, hbf);

  // phase D: fused per-token MLP -> out (4096 x 424)
  phase_d2<<<dim3(4, 424), dim3(512), 0, stream>>>(hbf, W1b, tpb1, tplng, tplnb, W2b, tpb2, tpW3, tpb3, out);
}